// Round 2
// baseline (171.661 us; speedup 1.0000x reference)
//
#include <hip/hip_runtime.h>

#define NN 50000
#define KK 32
#define FD 128   // in_feats == out_feats == 128

// ---- helpers -------------------------------------------------------------
__device__ __forceinline__ float f4e(const float4 v, int i) {
    switch (i & 3) { case 0: return v.x; case 1: return v.y; case 2: return v.z; default: return v.w; }
}

// ---- Kernel A: y = relu(x @ W^T + b) ------------------------------------
// Block 256 threads. Static LDS 64KB: WT half-tile [128 i][64 o] (XOR-swizzled)
// + x tile [64 rows][128 i] (XOR-swizzled). Two o-passes of 64 outputs each.
// Thread layout: og = tid&15 (4 outputs via float4), rsel = tid>>4 (4 rows).
// Per i4 step: 4 x-float4 reads (2-way bcast) + 4 W-float4 reads (conflict-
// free via swizzle) + 64 FMA -> VALU-bound.
__global__ __launch_bounds__(256) void linrelu_kernel(
    const float* __restrict__ x, const float* __restrict__ W,
    const float* __restrict__ b, float* __restrict__ y, int n_tiles)
{
    __shared__ float WT[FD * 64];   // 32 KB, WT[i*64 + (o ^ ((i&7)<<2))]
    __shared__ float xs[64 * FD];   // 32 KB, xs[r*128 + (i ^ ((r&7)<<2))]
    const int tid  = threadIdx.x;
    const int og   = tid & 15;
    const int o0l  = og << 2;       // local o within the 64-wide half
    const int rsel = tid >> 4;
    const int r0   = rsel << 2;

    for (int p = 0; p < 2; ++p) {
        // stage W half-tile, transposed + swizzled (writes: 4-way, one-time)
        for (int f = tid; f < 64 * FD; f += 256) {
            const int o = f >> 7;          // 0..63
            const int i = f & 127;
            WT[i * 64 + (o ^ ((i & 7) << 2))] = W[(p * 64 + o) * FD + i];
        }
        const float4 bv = *(const float4*)(b + p * 64 + o0l);
        __syncthreads();

        for (int t = blockIdx.x; t < n_tiles; t += gridDim.x) {
            const int base = t << 6;       // 64 rows per tile
            for (int f = tid; f < 64 * FD; f += 256) {
                const int r = f >> 7, i = f & 127;
                const int row = base + r;
                xs[r * FD + (i ^ ((r & 7) << 2))] = (row < NN) ? x[row * FD + i] : 0.0f;
            }
            __syncthreads();

            float acc[4][4];
            #pragma unroll
            for (int r = 0; r < 4; ++r) {
                acc[r][0] = bv.x; acc[r][1] = bv.y; acc[r][2] = bv.z; acc[r][3] = bv.w;
            }

            #pragma unroll 2
            for (int i4 = 0; i4 < 32; ++i4) {
                float4 xr[4];
                #pragma unroll
                for (int r = 0; r < 4; ++r) {
                    const int rr = r0 + r;
                    xr[r] = *(const float4*)(xs + rr * FD + ((i4 << 2) ^ ((rr & 7) << 2)));
                }
                #pragma unroll
                for (int di = 0; di < 4; ++di) {
                    const int i = (i4 << 2) + di;
                    const float4 w4 = *(const float4*)(WT + i * 64 + (o0l ^ ((i & 7) << 2)));
                    #pragma unroll
                    for (int r = 0; r < 4; ++r) {
                        const float xv = f4e(xr[r], di);
                        acc[r][0] = fmaf(xv, w4.x, acc[r][0]);
                        acc[r][1] = fmaf(xv, w4.y, acc[r][1]);
                        acc[r][2] = fmaf(xv, w4.z, acc[r][2]);
                        acc[r][3] = fmaf(xv, w4.w, acc[r][3]);
                    }
                }
            }

            #pragma unroll
            for (int r = 0; r < 4; ++r) {
                const int row = base + r0 + r;
                if (row < NN) {
                    float4 o4;
                    o4.x = fmaxf(acc[r][0], 0.f);
                    o4.y = fmaxf(acc[r][1], 0.f);
                    o4.z = fmaxf(acc[r][2], 0.f);
                    o4.w = fmaxf(acc[r][3], 0.f);
                    *(float4*)(y + row * FD + p * 64 + o0l) = o4;
                }
            }
            __syncthreads();   // xs reuse next tile / WT reuse next pass
        }
        __syncthreads();
    }
}

// ---- Kernel B: out[n,:] = max_k y[neigh[n,k],:] --------------------------
// 8 nodes per 256-thread block; 32-lane group per node; float4 per lane.
// Each neighbor row read is one coalesced 512B burst; y (25.6MB) is
// L2/L3-resident so the 819MB of gather traffic is served from cache.
// NOTE: harness delivers integer inputs as int32 (NOT the reference's int64).
__global__ __launch_bounds__(256) void gathermax_kernel(
    const int* __restrict__ neigh, const float* __restrict__ y,
    float* __restrict__ out)
{
    const int tid  = threadIdx.x;
    const int lane = tid & 31;
    const int n    = (blockIdx.x << 3) + (tid >> 5);
    if (n >= NN) return;
    const int myidx = neigh[n * KK + lane];                   // coalesced 128B/group
    float4 acc = make_float4(0.f, 0.f, 0.f, 0.f);             // relu output >= 0
    #pragma unroll 8
    for (int k = 0; k < KK; ++k) {
        const int j = __shfl(myidx, k, 32);
        const float4 v = *(const float4*)(y + j * FD + (lane << 2));
        acc.x = fmaxf(acc.x, v.x);
        acc.y = fmaxf(acc.y, v.y);
        acc.z = fmaxf(acc.z, v.z);
        acc.w = fmaxf(acc.w, v.w);
    }
    *(float4*)(out + n * FD + (lane << 2)) = acc;
}

// ---- Fallback (only if ws too small): fused per-node compute -------------
__global__ __launch_bounds__(128) void fused_fallback_kernel(
    const float* __restrict__ x, const int* __restrict__ neigh,
    const float* __restrict__ W, const float* __restrict__ b,
    float* __restrict__ out)
{
    __shared__ float xsh[KK * FD];
    __shared__ int sidx[KK];
    const int n = blockIdx.x;
    const int tid = threadIdx.x;
    if (tid < KK) sidx[tid] = neigh[n * KK + tid];
    __syncthreads();
    for (int f = tid; f < KK * FD; f += 128) {
        const int k = f >> 7, i = f & 127;
        xsh[f] = x[(long long)sidx[k] * FD + i];
    }
    __syncthreads();
    const int o = tid;
    float acc[KK];
    #pragma unroll
    for (int k = 0; k < KK; ++k) acc[k] = 0.f;
    for (int i4 = 0; i4 < 32; ++i4) {
        const float4 w4 = *(const float4*)(W + o * FD + (i4 << 2));
        #pragma unroll
        for (int k = 0; k < KK; ++k) {
            const float4 xv = *(const float4*)(xsh + k * FD + (i4 << 2));
            acc[k] = fmaf(w4.x, xv.x, acc[k]);
            acc[k] = fmaf(w4.y, xv.y, acc[k]);
            acc[k] = fmaf(w4.z, xv.z, acc[k]);
            acc[k] = fmaf(w4.w, xv.w, acc[k]);
        }
    }
    const float bo = b[o];
    float m = 0.f;
    #pragma unroll
    for (int k = 0; k < KK; ++k) m = fmaxf(m, acc[k] + bo);
    out[(long long)n * FD + o] = m;
}

// ---- launch --------------------------------------------------------------
extern "C" void kernel_launch(void* const* d_in, const int* in_sizes, int n_in,
                              void* d_out, int out_size, void* d_ws, size_t ws_size,
                              hipStream_t stream) {
    const float* x     = (const float*)d_in[0];
    const int*   neigh = (const int*)d_in[1];    // int inputs arrive as int32
    const float* W     = (const float*)d_in[2];
    const float* b     = (const float*)d_in[3];
    float* out = (float*)d_out;

    const size_t ybytes = (size_t)NN * FD * sizeof(float);
    if (ws_size >= ybytes) {
        float* y = (float*)d_ws;
        const int n_tiles = (NN + 63) / 64;   // 782
        linrelu_kernel<<<dim3(512), dim3(256), 0, stream>>>(x, W, b, y, n_tiles);
        gathermax_kernel<<<dim3((NN + 7) / 8), dim3(256), 0, stream>>>(neigh, y, out);
    } else {
        fused_fallback_kernel<<<dim3(NN), dim3(128), 0, stream>>>(x, neigh, W, b, out);
    }
}

// Round 3
// 69.486 us; speedup vs baseline: 2.4705x; 2.4705x over previous
//
#include <hip/hip_runtime.h>

#define NN 50000
#define KK 32
#define FD 128   // in_feats == out_feats == 128

typedef __attribute__((ext_vector_type(8))) short bf16x8;   // MFMA A/B frag (8 bf16)
typedef __attribute__((ext_vector_type(4))) float f32x4;    // MFMA C/D frag

// fp32 -> bf16 round-to-nearest-even
__device__ __forceinline__ ushort f2bf(float f) {
    uint u = __float_as_uint(f);
    uint r = (u + 0x7fffu + ((u >> 16) & 1u)) >> 16;
    return (ushort)r;
}
__device__ __forceinline__ float bf2f(ushort h) {
    return __uint_as_float(((uint)h) << 16);
}

// ---- Kernel A: ybf = bf16(relu(x @ W^T + b)) via MFMA --------------------
// Block 256 = 4 waves; each wave does a 16-node x 128-o tile per iteration.
// W staged once per block into LDS as bf16, XOR-swizzled (byte ^= (o&7)<<4)
// so the B-fragment ds_read_b128 is max 2-way bank conflict (free, m136).
// A-frags: each lane loads 8 contiguous fp32 of x (row = lane&15,
// cols k0 + (lane>>4)*8) and converts. D layout: row=(lane>>4)*4+r, col=lane&15.
__global__ __launch_bounds__(256) void linrelu_mfma_kernel(
    const float* __restrict__ x, const float* __restrict__ W,
    const float* __restrict__ b, ushort* __restrict__ ybf, int n_tiles)
{
    __shared__ ushort Wl[FD * FD];   // 32 KB bf16, byte = o*256 + i*2, ^((o&7)<<4)
    const int tid  = threadIdx.x;
    const int lane = tid & 63;
    const int wv   = tid >> 6;
    const int l15  = lane & 15;
    const int lq   = lane >> 4;      // 0..3

    // stage W (fp32 -> bf16, swizzled); 4096 float4 chunks / 256 threads
    for (int c = tid; c < (FD * FD) / 4; c += 256) {
        const int o = (c << 2) >> 7;       // row (out feature)
        const int i = (c << 2) & 127;      // col (in feature), multiple of 4
        const float4 w4 = *(const float4*)(W + o * FD + i);
        ushort4 h;
        h.x = f2bf(w4.x); h.y = f2bf(w4.y); h.z = f2bf(w4.z); h.w = f2bf(w4.w);
        const int byte = (o * 256 + i * 2) ^ ((o & 7) << 4);   // 8B-aligned, XOR bits 4-6
        *(ushort4*)((char*)Wl + byte) = h;
    }
    float bias_r[8];
    #pragma unroll
    for (int j = 0; j < 8; ++j) bias_r[j] = b[j * 16 + l15];
    __syncthreads();

    for (int t = blockIdx.x; t < n_tiles; t += gridDim.x) {
        const int nb  = t * 64 + wv * 16;
        const int row = nb + l15;
        const bool rv = (row < NN);

        bf16x8 af[4];
        #pragma unroll
        for (int k0 = 0; k0 < 4; ++k0) {
            float4 v0 = make_float4(0.f, 0.f, 0.f, 0.f), v1 = v0;
            if (rv) {
                const float* xp = x + (size_t)row * FD + (k0 << 5) + (lq << 3);
                v0 = *(const float4*)xp;
                v1 = *(const float4*)(xp + 4);
            }
            bf16x8 a;
            a[0] = (short)f2bf(v0.x); a[1] = (short)f2bf(v0.y);
            a[2] = (short)f2bf(v0.z); a[3] = (short)f2bf(v0.w);
            a[4] = (short)f2bf(v1.x); a[5] = (short)f2bf(v1.y);
            a[6] = (short)f2bf(v1.z); a[7] = (short)f2bf(v1.w);
            af[k0] = a;
        }

        f32x4 acc[8];
        #pragma unroll
        for (int j = 0; j < 8; ++j) acc[j] = (f32x4){0.f, 0.f, 0.f, 0.f};

        #pragma unroll
        for (int k0 = 0; k0 < 4; ++k0) {
            #pragma unroll
            for (int j = 0; j < 8; ++j) {
                const int o    = (j << 4) + l15;
                const int byte = (o * 256 + ((k0 << 5) + (lq << 3)) * 2) ^ ((o & 7) << 4);
                const bf16x8 bfr = *(const bf16x8*)((const char*)Wl + byte);
                acc[j] = __builtin_amdgcn_mfma_f32_16x16x32_bf16(af[k0], bfr, acc[j], 0, 0, 0);
            }
        }

        #pragma unroll
        for (int j = 0; j < 8; ++j) {
            #pragma unroll
            for (int r = 0; r < 4; ++r) {
                const int m = nb + (lq << 2) + r;
                if (m < NN) {
                    float v = fmaxf(acc[j][r] + bias_r[j], 0.f);
                    ybf[(size_t)m * FD + (j << 4) + l15] = f2bf(v);
                }
            }
        }
    }
}

// ---- Kernel B: out[n,:] = max_k ybf[neigh[n,k],:] ------------------------
// 16 lanes per node, 16B (8 bf16) per lane per neighbor row (256B/row burst).
// y bf16 = 12.8 MB -> ~2x L2 coverage + half the gather bytes vs fp32.
__global__ __launch_bounds__(256) void gathermax_bf16_kernel(
    const int* __restrict__ neigh, const ushort* __restrict__ ybf,
    float* __restrict__ out)
{
    const int tid   = threadIdx.x;
    const int lane  = tid & 63;
    const int l15   = lane & 15;
    const int gbase = lane & 48;                 // 16-lane group base within wave
    const int n     = (blockIdx.x * 256 + tid) >> 4;
    if (n >= NN) return;

    const int ia = neigh[n * KK + l15];          // neighbors 0..15
    const int ib = neigh[n * KK + 16 + l15];     // neighbors 16..31

    float acc[8];
    #pragma unroll
    for (int e = 0; e < 8; ++e) acc[e] = 0.f;    // relu output >= 0

    #pragma unroll
    for (int k = 0; k < 16; ++k) {
        const int j = __shfl(ia, gbase + k);
        const uint4 v = *(const uint4*)(ybf + (size_t)j * FD + (l15 << 3));
        acc[0] = fmaxf(acc[0], bf2f((ushort)(v.x & 0xffffu)));
        acc[1] = fmaxf(acc[1], bf2f((ushort)(v.x >> 16)));
        acc[2] = fmaxf(acc[2], bf2f((ushort)(v.y & 0xffffu)));
        acc[3] = fmaxf(acc[3], bf2f((ushort)(v.y >> 16)));
        acc[4] = fmaxf(acc[4], bf2f((ushort)(v.z & 0xffffu)));
        acc[5] = fmaxf(acc[5], bf2f((ushort)(v.z >> 16)));
        acc[6] = fmaxf(acc[6], bf2f((ushort)(v.w & 0xffffu)));
        acc[7] = fmaxf(acc[7], bf2f((ushort)(v.w >> 16)));
    }
    #pragma unroll
    for (int k = 0; k < 16; ++k) {
        const int j = __shfl(ib, gbase + k);
        const uint4 v = *(const uint4*)(ybf + (size_t)j * FD + (l15 << 3));
        acc[0] = fmaxf(acc[0], bf2f((ushort)(v.x & 0xffffu)));
        acc[1] = fmaxf(acc[1], bf2f((ushort)(v.x >> 16)));
        acc[2] = fmaxf(acc[2], bf2f((ushort)(v.y & 0xffffu)));
        acc[3] = fmaxf(acc[3], bf2f((ushort)(v.y >> 16)));
        acc[4] = fmaxf(acc[4], bf2f((ushort)(v.z & 0xffffu)));
        acc[5] = fmaxf(acc[5], bf2f((ushort)(v.z >> 16)));
        acc[6] = fmaxf(acc[6], bf2f((ushort)(v.w & 0xffffu)));
        acc[7] = fmaxf(acc[7], bf2f((ushort)(v.w >> 16)));
    }

    float* op = out + (size_t)n * FD + (l15 << 3);
    *(float4*)op       = make_float4(acc[0], acc[1], acc[2], acc[3]);
    *(float4*)(op + 4) = make_float4(acc[4], acc[5], acc[6], acc[7]);
}

// ---- Fallback (only if ws too small): fused per-node fp32 compute --------
__global__ __launch_bounds__(128) void fused_fallback_kernel(
    const float* __restrict__ x, const int* __restrict__ neigh,
    const float* __restrict__ W, const float* __restrict__ b,
    float* __restrict__ out)
{
    __shared__ float xsh[KK * FD];
    __shared__ int sidx[KK];
    const int n = blockIdx.x;
    const int tid = threadIdx.x;
    if (tid < KK) sidx[tid] = neigh[n * KK + tid];
    __syncthreads();
    for (int f = tid; f < KK * FD; f += 128) {
        const int k = f >> 7, i = f & 127;
        xsh[f] = x[(size_t)sidx[k] * FD + i];
    }
    __syncthreads();
    const int o = tid;
    float acc[KK];
    #pragma unroll
    for (int k = 0; k < KK; ++k) acc[k] = 0.f;
    for (int i4 = 0; i4 < 32; ++i4) {
        const float4 w4 = *(const float4*)(W + o * FD + (i4 << 2));
        #pragma unroll
        for (int k = 0; k < KK; ++k) {
            const float4 xv = *(const float4*)(xsh + k * FD + (i4 << 2));
            acc[k] = fmaf(w4.x, xv.x, acc[k]);
            acc[k] = fmaf(w4.y, xv.y, acc[k]);
            acc[k] = fmaf(w4.z, xv.z, acc[k]);
            acc[k] = fmaf(w4.w, xv.w, acc[k]);
        }
    }
    const float bo = b[o];
    float m = 0.f;
    #pragma unroll
    for (int k = 0; k < KK; ++k) m = fmaxf(m, acc[k] + bo);
    out[(size_t)n * FD + o] = m;
}

// ---- launch --------------------------------------------------------------
extern "C" void kernel_launch(void* const* d_in, const int* in_sizes, int n_in,
                              void* d_out, int out_size, void* d_ws, size_t ws_size,
                              hipStream_t stream) {
    const float* x     = (const float*)d_in[0];
    const int*   neigh = (const int*)d_in[1];    // harness delivers ints as int32
    const float* W     = (const float*)d_in[2];
    const float* b     = (const float*)d_in[3];
    float* out = (float*)d_out;

    const size_t ybytes = (size_t)NN * FD * sizeof(ushort);   // 12.8 MB bf16
    if (ws_size >= ybytes) {
        ushort* ybf = (ushort*)d_ws;
        const int n_tiles = (NN + 63) / 64;   // 782
        linrelu_mfma_kernel<<<dim3(n_tiles), dim3(256), 0, stream>>>(x, W, b, ybf, n_tiles);
        gathermax_bf16_kernel<<<dim3((NN * 16 + 255) / 256), dim3(256), 0, stream>>>(neigh, ybf, out);
    } else {
        fused_fallback_kernel<<<dim3(NN), dim3(128), 0, stream>>>(x, neigh, W, b, out);
    }
}

// Round 4
// 67.820 us; speedup vs baseline: 2.5311x; 1.0246x over previous
//
#include <hip/hip_runtime.h>

#define NN 50000
#define KK 32
#define FD 128   // in_feats == out_feats == 128

typedef __attribute__((ext_vector_type(8))) short bf16x8;   // MFMA A/B frag (8 bf16)
typedef __attribute__((ext_vector_type(4))) float f32x4;    // MFMA C/D frag
typedef __attribute__((ext_vector_type(4))) uint  u32x4;

// fp32 -> bf16 round-to-nearest-even
__device__ __forceinline__ ushort f2bf(float f) {
    uint u = __float_as_uint(f);
    uint r = (u + 0x7fffu + ((u >> 16) & 1u)) >> 16;
    return (ushort)r;
}
__device__ __forceinline__ float bf2f(ushort h) {
    return __uint_as_float(((uint)h) << 16);
}

// ---- Kernel A: ybf = bf16(relu(x @ W^T + b)) via MFMA, operands swapped --
// D = W_frag(A) * x_frag(B): D col = node = lane&15, D row = o = (lane>>4)*4+r.
// -> per-lane acc[j][0..3] are 4 CONTIGUOUS o's => ushort4 stores (8 per lane
// instead of 32 scalar stores). W staged once in LDS (bf16, XOR-swizzled,
// <=2-way bank conflict = free). Bias folded into MFMA C-init. x loads issued
// before the staging barrier to overlap global latency.
__global__ __launch_bounds__(256) void linrelu_mfma_kernel(
    const float* __restrict__ x, const float* __restrict__ W,
    const float* __restrict__ b, ushort* __restrict__ ybf)
{
    __shared__ ushort Wl[FD * FD];   // 32 KB, byte = (o*256 + i*2) ^ ((o&7)<<4)
    const int tid  = threadIdx.x;
    const int lane = tid & 63;
    const int wv   = tid >> 6;
    const int l15  = lane & 15;
    const int lq   = lane >> 4;      // 0..3

    // stage W (fp32 -> bf16, swizzled)
    for (int c = tid; c < (FD * FD) / 4; c += 256) {
        const int o = (c << 2) >> 7;
        const int i = (c << 2) & 127;
        const float4 w4 = *(const float4*)(W + o * FD + i);
        ushort4 h;
        h.x = f2bf(w4.x); h.y = f2bf(w4.y); h.z = f2bf(w4.z); h.w = f2bf(w4.w);
        const int byte = (o * 256 + i * 2) ^ ((o & 7) << 4);
        *(ushort4*)((char*)Wl + byte) = h;
    }

    // bias as MFMA C-init: acc[j][r] sits at row o = j*16 + lq*4 + r
    f32x4 acc[8];
    #pragma unroll
    for (int j = 0; j < 8; ++j) {
        const float4 b4 = *(const float4*)(b + (j << 4) + (lq << 2));
        acc[j] = (f32x4){b4.x, b4.y, b4.z, b4.w};
    }

    const int node = blockIdx.x * 64 + wv * 16 + l15;   // B-operand column
    const bool rv  = (node < NN);

    // x B-frags: lane&15 = node col, k = lq*8 + e  (overlaps W staging)
    bf16x8 xf[4];
    #pragma unroll
    for (int k0 = 0; k0 < 4; ++k0) {
        float4 v0 = make_float4(0.f, 0.f, 0.f, 0.f), v1 = v0;
        if (rv) {
            const float* xp = x + (size_t)node * FD + (k0 << 5) + (lq << 3);
            v0 = *(const float4*)xp;
            v1 = *(const float4*)(xp + 4);
        }
        bf16x8 a;
        a[0] = (short)f2bf(v0.x); a[1] = (short)f2bf(v0.y);
        a[2] = (short)f2bf(v0.z); a[3] = (short)f2bf(v0.w);
        a[4] = (short)f2bf(v1.x); a[5] = (short)f2bf(v1.y);
        a[6] = (short)f2bf(v1.z); a[7] = (short)f2bf(v1.w);
        xf[k0] = a;
    }

    __syncthreads();

    #pragma unroll
    for (int k0 = 0; k0 < 4; ++k0) {
        #pragma unroll
        for (int j = 0; j < 8; ++j) {
            const int o    = (j << 4) + l15;   // A-frag: lane&15 = o row
            const int byte = (o * 256 + (((k0 << 5) + (lq << 3)) << 1)) ^ ((o & 7) << 4);
            const bf16x8 wf = *(const bf16x8*)((const char*)Wl + byte);
            acc[j] = __builtin_amdgcn_mfma_f32_16x16x32_bf16(wf, xf[k0], acc[j], 0, 0, 0);
        }
    }

    if (rv) {
        #pragma unroll
        for (int j = 0; j < 8; ++j) {
            ushort4 h;
            h.x = f2bf(fmaxf(acc[j][0], 0.f));
            h.y = f2bf(fmaxf(acc[j][1], 0.f));
            h.z = f2bf(fmaxf(acc[j][2], 0.f));
            h.w = f2bf(fmaxf(acc[j][3], 0.f));
            *(ushort4*)(ybf + (size_t)node * FD + (j << 4) + (lq << 2)) = h;
        }
    }
}

// ---- Kernel B: out[n,:] = max_k ybf[neigh[n,k],:] ------------------------
// 16 lanes/node, 8-deep batched gather for MLP: 8 broadcast index loads ->
// 8 independent uint4 loads in flight -> 64 fmax. NT stores keep y in cache.
__global__ __launch_bounds__(256) void gathermax_bf16_kernel(
    const int* __restrict__ neigh, const ushort* __restrict__ ybf,
    float* __restrict__ out)
{
    const int tid = threadIdx.x;
    const int l15 = tid & 15;
    const int n   = (blockIdx.x * 256 + tid) >> 4;   // grid exact: 50000*16/256
    const int* nb = neigh + n * KK;
    const int fo  = l15 << 3;

    float acc[8];
    #pragma unroll
    for (int e = 0; e < 8; ++e) acc[e] = 0.f;        // relu output >= 0

    #pragma unroll
    for (int k0 = 0; k0 < KK; k0 += 8) {
        int jx[8];
        #pragma unroll
        for (int u = 0; u < 8; ++u) jx[u] = nb[k0 + u];   // 16-lane broadcast, L1-hot
        u32x4 v[8];
        #pragma unroll
        for (int u = 0; u < 8; ++u)
            v[u] = *(const u32x4*)(ybf + (size_t)jx[u] * FD + fo);
        #pragma unroll
        for (int u = 0; u < 8; ++u) {
            acc[0] = fmaxf(acc[0], bf2f((ushort)(v[u].x & 0xffffu)));
            acc[1] = fmaxf(acc[1], bf2f((ushort)(v[u].x >> 16)));
            acc[2] = fmaxf(acc[2], bf2f((ushort)(v[u].y & 0xffffu)));
            acc[3] = fmaxf(acc[3], bf2f((ushort)(v[u].y >> 16)));
            acc[4] = fmaxf(acc[4], bf2f((ushort)(v[u].z & 0xffffu)));
            acc[5] = fmaxf(acc[5], bf2f((ushort)(v[u].z >> 16)));
            acc[6] = fmaxf(acc[6], bf2f((ushort)(v[u].w & 0xffffu)));
            acc[7] = fmaxf(acc[7], bf2f((ushort)(v[u].w >> 16)));
        }
    }

    float* op = out + (size_t)n * FD + (l15 << 3);
    f32x4 o0 = {acc[0], acc[1], acc[2], acc[3]};
    f32x4 o1 = {acc[4], acc[5], acc[6], acc[7]};
    __builtin_nontemporal_store(o0, (f32x4*)op);        // out is write-once:
    __builtin_nontemporal_store(o1, (f32x4*)(op + 4));  // don't evict y
}

// ---- Fallback (only if ws too small): fused per-node fp32 compute --------
__global__ __launch_bounds__(128) void fused_fallback_kernel(
    const float* __restrict__ x, const int* __restrict__ neigh,
    const float* __restrict__ W, const float* __restrict__ b,
    float* __restrict__ out)
{
    __shared__ float xsh[KK * FD];
    __shared__ int sidx[KK];
    const int n = blockIdx.x;
    const int tid = threadIdx.x;
    if (tid < KK) sidx[tid] = neigh[n * KK + tid];
    __syncthreads();
    for (int f = tid; f < KK * FD; f += 128) {
        const int k = f >> 7, i = f & 127;
        xsh[f] = x[(size_t)sidx[k] * FD + i];
    }
    __syncthreads();
    const int o = tid;
    float acc[KK];
    #pragma unroll
    for (int k = 0; k < KK; ++k) acc[k] = 0.f;
    for (int i4 = 0; i4 < 32; ++i4) {
        const float4 w4 = *(const float4*)(W + o * FD + (i4 << 2));
        #pragma unroll
        for (int k = 0; k < KK; ++k) {
            const float4 xv = *(const float4*)(xsh + k * FD + (i4 << 2));
            acc[k] = fmaf(w4.x, xv.x, acc[k]);
            acc[k] = fmaf(w4.y, xv.y, acc[k]);
            acc[k] = fmaf(w4.z, xv.z, acc[k]);
            acc[k] = fmaf(w4.w, xv.w, acc[k]);
        }
    }
    const float bo = b[o];
    float m = 0.f;
    #pragma unroll
    for (int k = 0; k < KK; ++k) m = fmaxf(m, acc[k] + bo);
    out[(size_t)n * FD + o] = m;
}

// ---- launch --------------------------------------------------------------
extern "C" void kernel_launch(void* const* d_in, const int* in_sizes, int n_in,
                              void* d_out, int out_size, void* d_ws, size_t ws_size,
                              hipStream_t stream) {
    const float* x     = (const float*)d_in[0];
    const int*   neigh = (const int*)d_in[1];    // harness delivers ints as int32
    const float* W     = (const float*)d_in[2];
    const float* b     = (const float*)d_in[3];
    float* out = (float*)d_out;

    const size_t ybytes = (size_t)NN * FD * sizeof(ushort);   // 12.8 MB bf16
    if (ws_size >= ybytes) {
        ushort* ybf = (ushort*)d_ws;
        const int n_tiles = (NN + 63) / 64;   // 782 (64 nodes per block)
        linrelu_mfma_kernel<<<dim3(n_tiles), dim3(256), 0, stream>>>(x, W, b, ybf);
        gathermax_bf16_kernel<<<dim3((NN * 16) / 256), dim3(256), 0, stream>>>(neigh, ybf, out);
    } else {
        fused_fallback_kernel<<<dim3(NN), dim3(128), 0, stream>>>(x, neigh, W, b, out);
    }
}